// Round 1
// baseline (375.876 us; speedup 1.0000x reference)
//
#include <hip/hip_runtime.h>

// LinearQuant: out[32,8192] = x[32,8192] @ (int8-valued-int32 W[8192,8192] * scaler)
// Memory-bound: 256 MiB weight stream, floor ~43 us @ 6.3 TB/s.
//
// Strategy:
//   prep_x: xt[k][b] = x[b][k] * scaler   (1 MiB scratch in d_ws, wave-uniform reads later)
//   main:   1 thread = 1 output column, 32 fp32 accumulators (full batch),
//           K split 32-way across blockIdx.y, atomicAdd into zeroed d_out.

#define IN_F   8192
#define OUT_F  8192
#define BATCH  32
#define KSPLIT 32
#define KCHUNK (IN_F / KSPLIT)   // 256

__global__ void prep_x_kernel(const float* __restrict__ x,
                              const float* __restrict__ scaler,
                              float* __restrict__ xt) {
    int i = blockIdx.x * 256 + threadIdx.x;   // 0 .. BATCH*IN_F-1
    int k = i >> 5;                           // feature index
    int b = i & 31;                           // batch index
    // x is only 1 MiB; strided reads are absorbed by L2. Writes coalesced.
    xt[i] = x[b * IN_F + k] * scaler[0];
}

__global__ __launch_bounds__(256, 4)
void lq_main_kernel(const int* __restrict__ w,
                    const float* __restrict__ xt,
                    float* __restrict__ out) {
    const int col = blockIdx.x * 256 + threadIdx.x;   // output column (coalesced over lanes)
    const int k0  = blockIdx.y * KCHUNK;              // this block's K-chunk

    float acc[BATCH];
#pragma unroll
    for (int b = 0; b < BATCH; ++b) acc[b] = 0.0f;

    const int*   wp = w  + (size_t)k0 * OUT_F + col;  // walk down column `col`
    const float* xp = xt + (size_t)k0 * BATCH;        // wave-uniform x rows

#pragma unroll 4
    for (int k = 0; k < KCHUNK; ++k) {
        float wv = (float)wp[(size_t)k * OUT_F];      // one coalesced 4B load/lane
        const float* xk = xp + k * BATCH;             // uniform address -> s_load
#pragma unroll
        for (int b = 0; b < BATCH; ++b)
            acc[b] = fmaf(xk[b], wv, acc[b]);         // v_fmac acc, s_x, v_w
    }

    float* op = out + col;
#pragma unroll
    for (int b = 0; b < BATCH; ++b)
        atomicAdd(op + (size_t)b * OUT_F, acc[b]);    // device-scope, XCD-safe
}

extern "C" void kernel_launch(void* const* d_in, const int* in_sizes, int n_in,
                              void* d_out, int out_size, void* d_ws, size_t ws_size,
                              hipStream_t stream) {
    const float* x = (const float*)d_in[0];
    const int*   w = (const int*)d_in[1];
    const float* s = (const float*)d_in[2];
    float* out = (float*)d_out;
    float* xt  = (float*)d_ws;                        // needs 1 MiB scratch

    // d_out is poisoned to 0xAA before every timed call -> zero it for atomics.
    hipMemsetAsync(d_out, 0, (size_t)out_size * sizeof(float), stream);

    prep_x_kernel<<<dim3((BATCH * IN_F) / 256), dim3(256), 0, stream>>>(x, s, xt);

    lq_main_kernel<<<dim3(OUT_F / 256, KSPLIT), dim3(256), 0, stream>>>(w, xt, out);
}